// Round 15
// baseline (139.732 us; speedup 1.0000x reference)
//
#include <hip/hip_runtime.h>
#include <stdint.h>

// DiagonalSSM: out = (scan_t tanh(exp(-A)*state + (x@Bw^T)_t)) @ Wo^T + bo
// B=8, S=2048, Din=Dstate=Dout=1024, fp32 in/out.
//
// Pipeline:
//   mega_prep: cvt x->bf16 | cvt Bw->bf16 | cvt Wo->bf16*(-2) | bias2 = bo+rowsum(Wo)
//   GEMM1 (m97-structure 128^2 tile, 4 waves, 16KiB LDS, 3-4 blocks/CU):
//        Bx = x@Bw^T  stored BF16 -> first half of d_out
//   scan (r-space, time-chunked w/ 384-step warmup, 2 chains/thread) -> bf16 ws
//   GEMM2: out = r @ (-2*Wo)^T + bias2 -> f32 d_out

typedef __attribute__((ext_vector_type(8))) short bf16x8;
typedef __attribute__((ext_vector_type(4))) float f32x4;
typedef __attribute__((ext_vector_type(8))) unsigned short u16x8;

#define C2F 2.88539008177792681472f  // 2*log2(e)
#define LOG2E 1.44269504088896340736f

static __device__ __forceinline__ unsigned short f2b(float f) {
  unsigned u = __builtin_bit_cast(unsigned, f);
  unsigned r = 0x7FFFu + ((u >> 16) & 1u);  // round-to-nearest-even
  return (unsigned short)((u + r) >> 16);
}

// global -> LDS async copy, 16B per lane; LDS dest = wave-uniform base + lane*16.
static __device__ __forceinline__ void gload_lds16(const void* g, void* l) {
  __builtin_amdgcn_global_load_lds(
      (const __attribute__((address_space(1))) void*)(uintptr_t)g,
      (__attribute__((address_space(3))) void*)(unsigned)(uintptr_t)l,
      16, 0, 0);
}

// ---------------- fused prep: cvt_x | cvt_Bw | cvt_Wo(-2) | bias2 ----------------
__global__ __launch_bounds__(256) void mega_prep(const float* __restrict__ x,
                                                 const float* __restrict__ Bw,
                                                 const float* __restrict__ Wo,
                                                 const float* __restrict__ bo,
                                                 unsigned short* __restrict__ x_bf,
                                                 unsigned short* __restrict__ Bw_bf,
                                                 unsigned short* __restrict__ Wo_bf,
                                                 float* __restrict__ bias2) {
  const int bid = blockIdx.x;
  if (bid < 9216) {
    const float* in;
    unsigned short* out;
    float scale;
    int i;
    if (bid < 8192)      { in = x;  out = x_bf;  scale = 1.0f;  i = bid * 256 + threadIdx.x; }
    else if (bid < 8704) { in = Bw; out = Bw_bf; scale = 1.0f;  i = (bid - 8192) * 256 + threadIdx.x; }
    else                 { in = Wo; out = Wo_bf; scale = -2.0f; i = (bid - 8704) * 256 + threadIdx.x; }
    const float4* p = (const float4*)in;
    float4 v0 = p[2 * (size_t)i];
    float4 v1 = p[2 * (size_t)i + 1];
    u16x8 o;
    o[0] = f2b(v0.x * scale); o[1] = f2b(v0.y * scale);
    o[2] = f2b(v0.z * scale); o[3] = f2b(v0.w * scale);
    o[4] = f2b(v1.x * scale); o[5] = f2b(v1.y * scale);
    o[6] = f2b(v1.z * scale); o[7] = f2b(v1.w * scale);
    *(u16x8*)(out + 8 * (size_t)i) = o;
  } else {
    const int o = (bid - 9216) * 4 + (threadIdx.x >> 6);
    const int lane = threadIdx.x & 63;
    const float4* row = (const float4*)(Wo + (size_t)o * 1024);
    float s = 0.0f;
#pragma unroll
    for (int k = 0; k < 4; ++k) {
      float4 v = row[lane + k * 64];
      s += v.x + v.y + v.z + v.w;
    }
#pragma unroll
    for (int off = 32; off; off >>= 1) s += __shfl_down(s, off);
    if (lane == 0) bias2[o] = s + bo[o];
  }
}

// ======== 128x128-tile GEMM (m97 structure), C[M][N] = A[M][K] @ B[N][K]^T ========
// 4 waves (2m x 2n), wave tile 64x64 (4x4 16x16x32 frags). BK=32. LDS = 2 x 8KB
// (single-buffered). Plain __syncthreads loop — NO explicit waits: at 3-4 blocks/CU
// (16KiB LDS, grid 1024 = 4/CU), other blocks' MFMA hides this block's barrier
// drains (m114 implicit overlap — what the 256^2/1-block variants could never get).
// T2 both-sides swizzle per 8KB block (conflict-free, proven):
//   byte(row,chunk) = (row>>1)*128 + ((((row&1)<<2)+chunk) ^ ((row>>1)&7))*16
// T1 XCD-chunked mapping: each XCD owns 128 contiguous tiles = 16 A-panel rows
// (16 x 256KB = 4MB = its L2); B panels (2MB) L2-resident.
// TRANSPOSED ACC: mfma(b_frag, a_frag) = D^T -> lane&15 = M-row, reg = 4 N-cols.
// MODE 0: store acc as BF16 pairs (Bx)   MODE 1: store acc + bias2 as f32 (out)
template <int MODE>
__global__ __launch_bounds__(256, 3) void gemm128(const unsigned short* __restrict__ A,
                                                  const unsigned short* __restrict__ B,
                                                  void* __restrict__ Cv,
                                                  const float* __restrict__ bv,
                                                  int M, int N, int K) {
  __shared__ char lds[2][8192];  // [op][8KB] = 16 KiB
  const int tid = threadIdx.x;
  const int wave = tid >> 6, lane = tid & 63;
  const int wr = wave >> 1, wc = wave & 1;

  // T1: XCD-chunked block mapping (grid multiple of 8; bijective).
  const int nbn = N >> 7;
  const int per = gridDim.x >> 3;
  const int tilei = (blockIdx.x & 7) * per + (blockIdx.x >> 3);
  const int m0 = (tilei / nbn) << 7;
  const int n0 = (tilei % nbn) << 7;

  // Staging: per issue i (0..1), linear LDS offset o = i*4096 + wave*1024 + lane*16
  // within an 8KB block. Invert swizzle -> (row, chunk) to fetch from global.
  int soff[2];
#pragma unroll
  for (int i = 0; i < 2; ++i) {
    int o = i * 4096 + wave * 1024 + lane * 16;
    int rp = o >> 7;
    int p = ((o >> 4) & 7) ^ (rp & 7);
    int row = rp * 2 + (p >> 2);
    int chunk = p & 3;
    soff[i] = row * K + chunk * 8;  // element offset within [128 rows][32 k] block
  }
  const unsigned short* Abase = A + (size_t)m0 * K;
  const unsigned short* Bbase = B + (size_t)n0 * K;

  // Swizzled read bases (frag offsets are +f*1024: (row>>1)&7 invariant mod 16 rows)
  const int l15 = lane & 15, ck = lane >> 4;
  const int ra = wr * 64 + l15;
  const int rb = wc * 64 + l15;
  const int baseA = (ra >> 1) * 128 + ((((ra & 1) << 2) + ck) ^ ((ra >> 1) & 7)) * 16;
  const int baseB = (rb >> 1) * 128 + ((((rb & 1) << 2) + ck) ^ ((rb >> 1) & 7)) * 16;

  // accT[nf][mf]: TRANSPOSED accumulator (reg dim = N-cols).
  f32x4 accT[4][4] = {};

#define MFMA_(a_, b_, c_) __builtin_amdgcn_mfma_f32_16x16x32_bf16(a_, b_, c_, 0, 0, 0)

  for (int k0 = 0; k0 < K; k0 += 32) {
#pragma unroll
    for (int i = 0; i < 2; ++i) {
      gload_lds16(Abase + k0 + soff[i], &lds[0][i * 4096 + wave * 1024]);
      gload_lds16(Bbase + k0 + soff[i], &lds[1][i * 4096 + wave * 1024]);
    }
    __syncthreads();  // drains vmcnt -> staged data visible to all waves
    bf16x8 rA[4], rB[4];
#pragma unroll
    for (int f = 0; f < 4; ++f)
      rB[f] = *(const bf16x8*)(&lds[1][baseB + f * 1024]);
#pragma unroll
    for (int f = 0; f < 4; ++f)
      rA[f] = *(const bf16x8*)(&lds[0][baseA + f * 1024]);
#pragma unroll
    for (int mf = 0; mf < 4; ++mf)
#pragma unroll
      for (int nf = 0; nf < 4; ++nf)
        accT[nf][mf] = MFMA_(rB[nf], rA[mf], accT[nf][mf]);
    __syncthreads();  // all reads done before next iteration's stage overwrites
  }
#undef MFMA_

  // Epilogue (transposed acc): lane&15 = M-row, (lane>>4)*4+reg = 4 consecutive N-cols.
  const int cm = lane & 15;
  const int cn = (lane >> 4) * 4;
#pragma unroll
  for (int nf = 0; nf < 4; ++nf) {
    const int gn = n0 + wc * 64 + nf * 16 + cn;
#pragma unroll
    for (int mf = 0; mf < 4; ++mf) {
      const int gm = m0 + wr * 64 + mf * 16 + cm;
      f32x4 v = accT[nf][mf];
      if constexpr (MODE == 0) {
        // plain Bx -> bf16 packed pair store (8B)
        unsigned lo, hi;
        asm("v_cvt_pk_bf16_f32 %0, %1, %2" : "=v"(lo) : "v"(v[0]), "v"(v[1]));
        asm("v_cvt_pk_bf16_f32 %0, %1, %2" : "=v"(hi) : "v"(v[2]), "v"(v[3]));
        uint2 st; st.x = lo; st.y = hi;
        *(uint2*)((unsigned short*)Cv + (size_t)gm * N + gn) = st;
      } else {
        const f32x4 bb = *(const f32x4*)(bv + gn);
        v = v + bb;
        *(f32x4*)((float*)Cv + (size_t)gm * N + gn) = v;
      }
    }
  }
}

// ---------------- time-chunked scan, r-space, 2 adjacent channels/thread ----------------
// S split into 8 chunks of 256; chunk starts from state=0 at t = max(0, c*256-384):
// warmup contracts the wrong-init error by prod(dec*sech^2) ~ e^{-13} over 384 steps.
// Bx is BF16-packed (2 channels per u32). c = C2*bx + dkc folded in at buffer prep
// (off the dependent chain). Stores bf16(r) via cvt_pk.
__global__ __launch_bounds__(256) void scan_kernel(const unsigned* __restrict__ Bxp,
                                                   const float* __restrict__ Av,
                                                   unsigned short* __restrict__ h) {
  constexpr int S = 2048, D = 1024, CHUNK = 256, W = 384;
  const int bid = blockIdx.x;
  const int half = bid & 1;
  const int chunk = (bid >> 1) & 7;
  const int b = bid >> 4;
  const int p = half * 256 + threadIdx.x;  // 0..511
  const unsigned n0 = 2u * p;

  const float2 av = *(const float2*)(Av + n0);
  const float m2dk0 = -2.0f * C2F * __builtin_amdgcn_exp2f(-fminf(av.x, 10.0f) * LOG2E);
  const float m2dk1 = -2.0f * C2F * __builtin_amdgcn_exp2f(-fminf(av.y, 10.0f) * LOG2E);
  const float dkc0 = -0.5f * m2dk0;  // C2*dec
  const float dkc1 = -0.5f * m2dk1;

  // u32 index: (b*S + t)*D/2 + p
  const unsigned base = (unsigned)b * (S * D / 2) + p;
  const unsigned hbase = (unsigned)b * (S * D) + n0;
  const int t_store0 = chunk * CHUNK;
  const int t_start = (chunk * CHUNK - W) < 0 ? 0 : (chunk * CHUNK - W);
  const int t_end = t_store0 + CHUNK;
  constexpr unsigned DW = D / 2;

  unsigned uA[8], uB[8];
#pragma unroll
  for (int j = 0; j < 8; ++j) uA[j] = Bxp[base + (unsigned)(t_start + j) * DW];
#pragma unroll
  for (int j = 0; j < 8; ++j) uB[j] = Bxp[base + (unsigned)(t_start + 8 + j) * DW];

  float r0 = 0.5f, r1 = 0.5f;  // s = 1-2r = 0

  // unpack u32 (2 bf16) and fold in C2*bx + dkc (off the dependent chain)
#define PREP(CV, U)                                                       \
  {                                                                       \
    float lo = __builtin_bit_cast(float, (U) << 16);                      \
    float hi = __builtin_bit_cast(float, (U) & 0xFFFF0000u);              \
    (CV).x = fmaf(C2F, lo, dkc0);                                         \
    (CV).y = fmaf(C2F, hi, dkc1);                                         \
  }

#define STEP2(CV)                                         \
  {                                                       \
    float w0 = fmaf(m2dk0, r0, (CV).x);                   \
    float w1 = fmaf(m2dk1, r1, (CV).y);                   \
    float e0 = __builtin_amdgcn_exp2f(w0);                \
    float e1 = __builtin_amdgcn_exp2f(w1);                \
    r0 = __builtin_amdgcn_rcpf(e0 + 1.0f);                \
    r1 = __builtin_amdgcn_rcpf(e1 + 1.0f);                \
  }

#define STORE2(T_)                                                        \
  {                                                                       \
    unsigned pk;                                                          \
    asm("v_cvt_pk_bf16_f32 %0, %1, %2" : "=v"(pk) : "v"(r0), "v"(r1));    \
    *(unsigned*)(h + hbase + (unsigned)(T_) * D) = pk;                    \
  }

  // warmup (no stores); lengths are multiples of 16
  for (int t0 = t_start; t0 < t_store0; t0 += 16) {
    float2 c[8];
#pragma unroll
    for (int j = 0; j < 8; ++j) PREP(c[j], uA[j]);
#pragma unroll
    for (int j = 0; j < 8; ++j) uA[j] = Bxp[base + (unsigned)(t0 + 16 + j) * DW];
#pragma unroll
    for (int j = 0; j < 8; ++j) STEP2(c[j]);
#pragma unroll
    for (int j = 0; j < 8; ++j) PREP(c[j], uB[j]);
#pragma unroll
    for (int j = 0; j < 8; ++j) uB[j] = Bxp[base + (unsigned)(t0 + 24 + j) * DW];
#pragma unroll
    for (int j = 0; j < 8; ++j) STEP2(c[j]);
  }
  // stored region
  for (int t0 = t_store0; t0 < t_end; t0 += 16) {
    float2 c[8];
#pragma unroll
    for (int j = 0; j < 8; ++j) PREP(c[j], uA[j]);
    if (t0 + 16 < t_end) {
#pragma unroll
      for (int j = 0; j < 8; ++j) uA[j] = Bxp[base + (unsigned)(t0 + 16 + j) * DW];
    }
#pragma unroll
    for (int j = 0; j < 8; ++j) { STEP2(c[j]); STORE2(t0 + j); }
#pragma unroll
    for (int j = 0; j < 8; ++j) PREP(c[j], uB[j]);
    if (t0 + 24 < t_end) {
#pragma unroll
      for (int j = 0; j < 8; ++j) uB[j] = Bxp[base + (unsigned)(t0 + 24 + j) * DW];
    }
#pragma unroll
    for (int j = 0; j < 8; ++j) { STEP2(c[j]); STORE2(t0 + 8 + j); }
  }
#undef PREP
#undef STEP2
#undef STORE2
}

extern "C" void kernel_launch(void* const* d_in, const int* in_sizes, int n_in,
                              void* d_out, int out_size, void* d_ws, size_t ws_size,
                              hipStream_t stream) {
  const float* x  = (const float*)d_in[0];
  const float* Av = (const float*)d_in[1];
  const float* Bw = (const float*)d_in[2];
  const float* Wo = (const float*)d_in[3];
  const float* bo = (const float*)d_in[4];
  float* out = (float*)d_out;

  const int Bsz = 8, S = 2048, Din = 1024, Dst = 1024, Dout = 1024;
  const int M = Bsz * S;  // 16384

  char* ws = (char*)d_ws;
  unsigned short* x_bf  = (unsigned short*)ws;
  unsigned short* r_bf  = (unsigned short*)(ws + (size_t)M * Din * 2);
  unsigned short* Bw_bf = (unsigned short*)(ws + (size_t)M * Din * 4);
  unsigned short* Wo_bf = (unsigned short*)(ws + (size_t)M * Din * 4 + (size_t)Dst * Din * 2);
  float* bias2 = (float*)(ws + (size_t)M * Din * 4 + (size_t)Dst * Din * 4);

  // Bx (bf16, 32MB) lives in the first half of d_out; dead before GEMM2 rewrites out.
  unsigned short* Bx_bf = (unsigned short*)d_out;

  // One fused prep launch: cvt_x (8192 blocks) | cvt_Bw (512) | cvt_Wo (512) | bias2 (256)
  mega_prep<<<dim3(9472), 256, 0, stream>>>(x, Bw, Wo, bo, x_bf, Bw_bf, Wo_bf, bias2);

  gemm128<0><<<dim3((M / 128) * (Dst / 128)), 256, 0, stream>>>(x_bf, Bw_bf, (void*)Bx_bf,
                                                                nullptr, M, Dst, Din);
  scan_kernel<<<dim3(128), 256, 0, stream>>>((const unsigned*)Bx_bf, Av, r_bf);
  gemm128<1><<<dim3((M / 128) * (Dout / 128)), 256, 0, stream>>>(r_bf, Wo_bf, (void*)out,
                                                                 bias2, M, Dout, Dst);
}

// Round 16
// 130.293 us; speedup vs baseline: 1.0724x; 1.0724x over previous
//
#include <hip/hip_runtime.h>
#include <stdint.h>

// DiagonalSSM: out = (scan_t tanh(exp(-A)*state + (x@Bw^T)_t)) @ Wo^T + bo
// B=8, S=2048, Din=Dstate=Dout=1024, fp32 in/out.
//
// Pipeline (R9-proven GEMM/scan + single fused prep kernel) — session-best state:
//   mega_prep: cvt x->bf16 | cvt Bw->bf16 | cvt Wo->bf16*(-2) | bias2 = bo+rowsum(Wo)
//   GEMM1 (256^2, kslice ring-4, counted vmcnt, R9 protocol):
//        Bx = x@Bw^T  stored BF16 -> first half of d_out
//   scan (r-space, time-chunked w/ 384-step warmup, 2 chains/thread) -> bf16 ws
//   GEMM2: out = r @ (-2*Wo)^T + bias2 -> f32 d_out

typedef __attribute__((ext_vector_type(8))) short bf16x8;
typedef __attribute__((ext_vector_type(4))) float f32x4;
typedef __attribute__((ext_vector_type(8))) unsigned short u16x8;

#define C2F 2.88539008177792681472f  // 2*log2(e)
#define LOG2E 1.44269504088896340736f

static __device__ __forceinline__ unsigned short f2b(float f) {
  unsigned u = __builtin_bit_cast(unsigned, f);
  unsigned r = 0x7FFFu + ((u >> 16) & 1u);  // round-to-nearest-even
  return (unsigned short)((u + r) >> 16);
}

// global -> LDS async copy, 16B per lane; LDS dest = wave-uniform base + lane*16.
static __device__ __forceinline__ void gload_lds16(const void* g, void* l) {
  __builtin_amdgcn_global_load_lds(
      (const __attribute__((address_space(1))) void*)(uintptr_t)g,
      (__attribute__((address_space(3))) void*)(unsigned)(uintptr_t)l,
      16, 0, 0);
}

// ---------------- fused prep: cvt_x | cvt_Bw | cvt_Wo(-2) | bias2 ----------------
// blocks [0,8192): x (16M elems); [8192,8704): Bw (1M); [8704,9216): Wo (1M, *-2);
// [9216,9472): bias2 (4 rows/block, wave rowsum + bo).
__global__ __launch_bounds__(256) void mega_prep(const float* __restrict__ x,
                                                 const float* __restrict__ Bw,
                                                 const float* __restrict__ Wo,
                                                 const float* __restrict__ bo,
                                                 unsigned short* __restrict__ x_bf,
                                                 unsigned short* __restrict__ Bw_bf,
                                                 unsigned short* __restrict__ Wo_bf,
                                                 float* __restrict__ bias2) {
  const int bid = blockIdx.x;
  if (bid < 9216) {
    const float* in;
    unsigned short* out;
    float scale;
    int i;
    if (bid < 8192)      { in = x;  out = x_bf;  scale = 1.0f;  i = bid * 256 + threadIdx.x; }
    else if (bid < 8704) { in = Bw; out = Bw_bf; scale = 1.0f;  i = (bid - 8192) * 256 + threadIdx.x; }
    else                 { in = Wo; out = Wo_bf; scale = -2.0f; i = (bid - 8704) * 256 + threadIdx.x; }
    const float4* p = (const float4*)in;
    float4 v0 = p[2 * (size_t)i];
    float4 v1 = p[2 * (size_t)i + 1];
    u16x8 o;
    o[0] = f2b(v0.x * scale); o[1] = f2b(v0.y * scale);
    o[2] = f2b(v0.z * scale); o[3] = f2b(v0.w * scale);
    o[4] = f2b(v1.x * scale); o[5] = f2b(v1.y * scale);
    o[6] = f2b(v1.z * scale); o[7] = f2b(v1.w * scale);
    *(u16x8*)(out + 8 * (size_t)i) = o;
  } else {
    const int o = (bid - 9216) * 4 + (threadIdx.x >> 6);
    const int lane = threadIdx.x & 63;
    const float4* row = (const float4*)(Wo + (size_t)o * 1024);
    float s = 0.0f;
#pragma unroll
    for (int k = 0; k < 4; ++k) {
      float4 v = row[lane + k * 64];
      s += v.x + v.y + v.z + v.w;
    }
#pragma unroll
    for (int off = 32; off; off >>= 1) s += __shfl_down(s, off);
    if (lane == 0) bias2[o] = s + bo[o];
  }
}

// ======== 256x256-tile GEMM, C[M][N] = A[M][K] @ B[N][K]^T, epilogue-fused ========
// R9-proven (passed, 44.4us): 8 waves (2m x 4n), 32 kslice-phases, 4-slot 128KiB
// ring. Phase: vmcnt(counted) ; barrier ; RD 12 ds_read ; lgkmcnt(0)+sched_barrier
// ; setprio(1) 32 MFMA setprio(0) ; barrier ; STAGE next piece into just-read slot.
// vmcnt(12) = 3 pieces (4 gloads each) in flight; tail 8/4/0.
// TRANSPOSED ACC: mfma(b_frag, a_frag) = D^T -> lane&15 = M-row, reg = 4 N-cols.
// LDS swizzle per 16KB block (0-conflict verified):
//   byte(row,chunk) = (row>>1)*128 + ((((row&1)<<2)+chunk) ^ ((row>>1)&7))*16
// MODE 0: store acc as BF16 pairs (Bx)   MODE 1: store acc + bias2 as f32 (out)
template <int MODE>
__global__ __launch_bounds__(512, 2) void gemm256(const unsigned short* __restrict__ A,
                                                  const unsigned short* __restrict__ B,
                                                  void* __restrict__ Cv,
                                                  const float* __restrict__ bv,
                                                  int M, int N, int K) {
  __shared__ char lds[4][2][16384];  // [ring slot][op][16KB] = 128 KiB
  const int tid = threadIdx.x;
  const int wave = tid >> 6, lane = tid & 63;
  const int wr = wave >> 2, wc = wave & 3;

  // T1: XCD-chunked block mapping (grid multiple of 8; bijective).
  const int nbn = N >> 8;
  const int per = gridDim.x >> 3;
  const int tilei = (blockIdx.x & 7) * per + (blockIdx.x >> 3);
  const int m0 = (tilei / nbn) << 8;
  const int n0 = (tilei % nbn) << 8;

  // Staging: per issue i, linear LDS offset o = i*8192 + wave*1024 + lane*16
  // within a 16KB block. Invert swizzle -> (row, chunk) to fetch from global.
  int soff[2];
#pragma unroll
  for (int i = 0; i < 2; ++i) {
    int o = i * 8192 + wave * 1024 + lane * 16;
    int rp = o >> 7;
    int p = ((o >> 4) & 7) ^ (rp & 7);
    int row = rp * 2 + (p >> 2);
    int chunk = p & 3;
    soff[i] = row * K + chunk * 8;  // element offset within [256 rows][32 k] block
  }
  const unsigned short* Abase = A + (size_t)m0 * K;
  const unsigned short* Bbase = B + (size_t)n0 * K;

  // stage piece (kslice) with global k-offset K0S into ring slot SLOT (4 gloads)
#define STAGEP(SLOT, K0S)                                                         \
  {                                                                               \
    _Pragma("unroll") for (int i = 0; i < 2; ++i) {                               \
      gload_lds16(Abase + (K0S) + soff[i], &lds[SLOT][0][i * 8192 + wave * 1024]); \
      gload_lds16(Bbase + (K0S) + soff[i], &lds[SLOT][1][i * 8192 + wave * 1024]); \
    }                                                                             \
  }

  // Swizzled read bases (frag offsets are +f*1024: (row>>1)&7 invariant mod 16 rows)
  const int l15 = lane & 15, ck = lane >> 4;
  const int ra = wr * 128 + l15;
  const int rb = wc * 64 + l15;
  const int baseA = (ra >> 1) * 128 + ((((ra & 1) << 2) + ck) ^ ((ra >> 1) & 7)) * 16;
  const int baseB = (rb >> 1) * 128 + ((((rb & 1) << 2) + ck) ^ ((rb >> 1) & 7)) * 16;

  // accT[nf][mf]: TRANSPOSED accumulator (reg dim = N-cols).
  f32x4 accT[4][8] = {};
  bf16x8 rA[8], rB[4];

#define MFMA_(a_, b_, c_) __builtin_amdgcn_mfma_f32_16x16x32_bf16(a_, b_, c_, 0, 0, 0)

  // One phase: compute kslice in SLOT; optionally stage K0S into the same SLOT after.
#define PHASE(SLOT, WAITN, DOSTAGE, K0S)                                          \
  {                                                                               \
    asm volatile("s_waitcnt vmcnt(" WAITN ")" ::: "memory");                      \
    __builtin_amdgcn_s_barrier();                                                 \
    _Pragma("unroll") for (int f = 0; f < 4; ++f)                                 \
        rB[f] = *(const bf16x8*)(&lds[SLOT][1][baseB + f * 1024]);                \
    _Pragma("unroll") for (int f = 0; f < 8; ++f)                                 \
        rA[f] = *(const bf16x8*)(&lds[SLOT][0][baseA + f * 1024]);                \
    asm volatile("s_waitcnt lgkmcnt(0)" ::: "memory");                            \
    __builtin_amdgcn_sched_barrier(0);                                            \
    __builtin_amdgcn_s_setprio(1);                                                \
    _Pragma("unroll") for (int mf = 0; mf < 8; ++mf)                              \
      _Pragma("unroll") for (int nf = 0; nf < 4; ++nf)                            \
        accT[nf][mf] = MFMA_(rB[nf], rA[mf], accT[nf][mf]);                       \
    __builtin_amdgcn_s_setprio(0);                                                \
    __builtin_amdgcn_s_barrier();                                                 \
    if (DOSTAGE) STAGEP(SLOT, K0S);                                               \
  }

  const int T = K / 64;  // 16 at K=1024; kslices NP = 2T = 32

  // Prologue: stage pieces 0..3 (slots 0..3).
  STAGEP(0, 0); STAGEP(1, 32); STAGEP(2, 64); STAGEP(3, 96);

  // Main: phases i = 2t, 2t+1; stage pieces i+4 (k = i*32+128) into same slot.
  for (int t = 0; t < T - 2; ++t) {
    const int sa = (t & 1) * 2;
    PHASE(sa,     "12", true, t * 64 + 128);
    PHASE(sa + 1, "12", true, t * 64 + 160);
  }
  {  // t = T-2: phases 28, 29 (no staging; waits 12, 8)
    const int sa = ((T - 2) & 1) * 2;
    PHASE(sa,     "12", false, 0);
    PHASE(sa + 1, "8",  false, 0);
  }
  {  // t = T-1: phases 30, 31 (waits 4, 0)
    const int sa = ((T - 1) & 1) * 2;
    PHASE(sa,     "4",  false, 0);
    PHASE(sa + 1, "0",  false, 0);
  }

#undef PHASE
#undef STAGEP
#undef MFMA_

  // Epilogue (transposed acc): lane&15 = M-row, (lane>>4)*4+reg = 4 consecutive N-cols.
  const int cm = lane & 15;
  const int cn = (lane >> 4) * 4;
#pragma unroll
  for (int nf = 0; nf < 4; ++nf) {
    const int gn = n0 + wc * 64 + nf * 16 + cn;
#pragma unroll
    for (int mf = 0; mf < 8; ++mf) {
      const int gm = m0 + wr * 128 + mf * 16 + cm;
      f32x4 v = accT[nf][mf];
      if constexpr (MODE == 0) {
        // plain Bx -> bf16 packed pair store (8B)
        unsigned lo, hi;
        asm("v_cvt_pk_bf16_f32 %0, %1, %2" : "=v"(lo) : "v"(v[0]), "v"(v[1]));
        asm("v_cvt_pk_bf16_f32 %0, %1, %2" : "=v"(hi) : "v"(v[2]), "v"(v[3]));
        uint2 st; st.x = lo; st.y = hi;
        *(uint2*)((unsigned short*)Cv + (size_t)gm * N + gn) = st;
      } else {
        const f32x4 bb = *(const f32x4*)(bv + gn);
        v = v + bb;
        *(f32x4*)((float*)Cv + (size_t)gm * N + gn) = v;
      }
    }
  }
}

// ---------------- time-chunked scan, r-space, 2 adjacent channels/thread ----------------
// S split into 8 chunks of 256; chunk starts from state=0 at t = max(0, c*256-384):
// warmup contracts the wrong-init error by prod(dec*sech^2) ~ e^{-13} over 384 steps.
// Bx is BF16-packed (2 channels per u32). c = C2*bx + dkc folded in at buffer prep
// (off the dependent chain). Stores bf16(r) via cvt_pk.
__global__ __launch_bounds__(256) void scan_kernel(const unsigned* __restrict__ Bxp,
                                                   const float* __restrict__ Av,
                                                   unsigned short* __restrict__ h) {
  constexpr int S = 2048, D = 1024, CHUNK = 256, W = 384;
  const int bid = blockIdx.x;
  const int half = bid & 1;
  const int chunk = (bid >> 1) & 7;
  const int b = bid >> 4;
  const int p = half * 256 + threadIdx.x;  // 0..511
  const unsigned n0 = 2u * p;

  const float2 av = *(const float2*)(Av + n0);
  const float m2dk0 = -2.0f * C2F * __builtin_amdgcn_exp2f(-fminf(av.x, 10.0f) * LOG2E);
  const float m2dk1 = -2.0f * C2F * __builtin_amdgcn_exp2f(-fminf(av.y, 10.0f) * LOG2E);
  const float dkc0 = -0.5f * m2dk0;  // C2*dec
  const float dkc1 = -0.5f * m2dk1;

  // u32 index: (b*S + t)*D/2 + p
  const unsigned base = (unsigned)b * (S * D / 2) + p;
  const unsigned hbase = (unsigned)b * (S * D) + n0;
  const int t_store0 = chunk * CHUNK;
  const int t_start = (chunk * CHUNK - W) < 0 ? 0 : (chunk * CHUNK - W);
  const int t_end = t_store0 + CHUNK;
  constexpr unsigned DW = D / 2;

  unsigned uA[8], uB[8];
#pragma unroll
  for (int j = 0; j < 8; ++j) uA[j] = Bxp[base + (unsigned)(t_start + j) * DW];
#pragma unroll
  for (int j = 0; j < 8; ++j) uB[j] = Bxp[base + (unsigned)(t_start + 8 + j) * DW];

  float r0 = 0.5f, r1 = 0.5f;  // s = 1-2r = 0

  // unpack u32 (2 bf16) and fold in C2*bx + dkc (off the dependent chain)
#define PREP(CV, U)                                                       \
  {                                                                       \
    float lo = __builtin_bit_cast(float, (U) << 16);                      \
    float hi = __builtin_bit_cast(float, (U) & 0xFFFF0000u);              \
    (CV).x = fmaf(C2F, lo, dkc0);                                         \
    (CV).y = fmaf(C2F, hi, dkc1);                                         \
  }

#define STEP2(CV)                                         \
  {                                                       \
    float w0 = fmaf(m2dk0, r0, (CV).x);                   \
    float w1 = fmaf(m2dk1, r1, (CV).y);                   \
    float e0 = __builtin_amdgcn_exp2f(w0);                \
    float e1 = __builtin_amdgcn_exp2f(w1);                \
    r0 = __builtin_amdgcn_rcpf(e0 + 1.0f);                \
    r1 = __builtin_amdgcn_rcpf(e1 + 1.0f);                \
  }

#define STORE2(T_)                                                        \
  {                                                                       \
    unsigned pk;                                                          \
    asm("v_cvt_pk_bf16_f32 %0, %1, %2" : "=v"(pk) : "v"(r0), "v"(r1));    \
    *(unsigned*)(h + hbase + (unsigned)(T_) * D) = pk;                    \
  }

  // warmup (no stores); lengths are multiples of 16
  for (int t0 = t_start; t0 < t_store0; t0 += 16) {
    float2 c[8];
#pragma unroll
    for (int j = 0; j < 8; ++j) PREP(c[j], uA[j]);
#pragma unroll
    for (int j = 0; j < 8; ++j) uA[j] = Bxp[base + (unsigned)(t0 + 16 + j) * DW];
#pragma unroll
    for (int j = 0; j < 8; ++j) STEP2(c[j]);
#pragma unroll
    for (int j = 0; j < 8; ++j) PREP(c[j], uB[j]);
#pragma unroll
    for (int j = 0; j < 8; ++j) uB[j] = Bxp[base + (unsigned)(t0 + 24 + j) * DW];
#pragma unroll
    for (int j = 0; j < 8; ++j) STEP2(c[j]);
  }
  // stored region
  for (int t0 = t_store0; t0 < t_end; t0 += 16) {
    float2 c[8];
#pragma unroll
    for (int j = 0; j < 8; ++j) PREP(c[j], uA[j]);
    if (t0 + 16 < t_end) {
#pragma unroll
      for (int j = 0; j < 8; ++j) uA[j] = Bxp[base + (unsigned)(t0 + 16 + j) * DW];
    }
#pragma unroll
    for (int j = 0; j < 8; ++j) { STEP2(c[j]); STORE2(t0 + j); }
#pragma unroll
    for (int j = 0; j < 8; ++j) PREP(c[j], uB[j]);
    if (t0 + 24 < t_end) {
#pragma unroll
      for (int j = 0; j < 8; ++j) uB[j] = Bxp[base + (unsigned)(t0 + 24 + j) * DW];
    }
#pragma unroll
    for (int j = 0; j < 8; ++j) { STEP2(c[j]); STORE2(t0 + 8 + j); }
  }
#undef PREP
#undef STEP2
#undef STORE2
}

extern "C" void kernel_launch(void* const* d_in, const int* in_sizes, int n_in,
                              void* d_out, int out_size, void* d_ws, size_t ws_size,
                              hipStream_t stream) {
  const float* x  = (const float*)d_in[0];
  const float* Av = (const float*)d_in[1];
  const float* Bw = (const float*)d_in[2];
  const float* Wo = (const float*)d_in[3];
  const float* bo = (const float*)d_in[4];
  float* out = (float*)d_out;

  const int Bsz = 8, S = 2048, Din = 1024, Dst = 1024, Dout = 1024;
  const int M = Bsz * S;  // 16384

  char* ws = (char*)d_ws;
  unsigned short* x_bf  = (unsigned short*)ws;
  unsigned short* r_bf  = (unsigned short*)(ws + (size_t)M * Din * 2);
  unsigned short* Bw_bf = (unsigned short*)(ws + (size_t)M * Din * 4);
  unsigned short* Wo_bf = (unsigned short*)(ws + (size_t)M * Din * 4 + (size_t)Dst * Din * 2);
  float* bias2 = (float*)(ws + (size_t)M * Din * 4 + (size_t)Dst * Din * 4);

  // Bx (bf16, 32MB) lives in the first half of d_out; dead before GEMM2 rewrites out.
  unsigned short* Bx_bf = (unsigned short*)d_out;

  // One fused prep launch: cvt_x (8192 blocks) | cvt_Bw (512) | cvt_Wo (512) | bias2 (256)
  mega_prep<<<dim3(9472), 256, 0, stream>>>(x, Bw, Wo, bo, x_bf, Bw_bf, Wo_bf, bias2);

  gemm256<0><<<dim3((M / 256) * (Dst / 256)), 512, 0, stream>>>(x_bf, Bw_bf, (void*)Bx_bf,
                                                                nullptr, M, Dst, Din);
  scan_kernel<<<dim3(128), 256, 0, stream>>>((const unsigned*)Bx_bf, Av, r_bf);
  gemm256<1><<<dim3((M / 256) * (Dout / 256)), 512, 0, stream>>>(r_bf, Wo_bf, (void*)out,
                                                                 bias2, M, Dout, Dst);
}